// Round 1
// baseline (791.848 us; speedup 1.0000x reference)
//
#include <hip/hip_runtime.h>
#include <hip/hip_bf16.h>
#include <math.h>

#define NN 50000
#define EE 800000
#define NPG 5000

__device__ __forceinline__ float gelu_exact(float v) {
    return 0.5f * v * (1.0f + erff(v * 0.70710678118654752440f));
}

// ---------------- column stats of x: sum, sumsq per column ----------------
__global__ __launch_bounds__(256) void colstats_kernel(const float* __restrict__ x,
                                                       float* __restrict__ sums, int n) {
    int col = threadIdx.x & 127;
    int half = threadIdx.x >> 7;               // 0/1
    int rowEnd = min(blockIdx.x * 512 + 512, n);
    float s = 0.f, s2 = 0.f;
    for (int r = blockIdx.x * 512 + half; r < rowEnd; r += 2) {
        float v = x[(size_t)r * 128 + col];
        s += v; s2 += v * v;
    }
    atomicAdd(&sums[col], s);
    atomicAdd(&sums[128 + col], s2);
}

__global__ void finalize_stats_kernel(float* __restrict__ stats, int n) {
    int c = threadIdx.x;   // 128 threads
    float sum = stats[c], sumsq = stats[128 + c];
    float mu = sum / (float)n;
    float var = (sumsq - sum * sum / (float)n) / (float)(n - 1);  // ddof=1
    stats[256 + c] = mu;
    stats[384 + c] = sqrtf(fmaxf(var, 0.f));
}

// ---------------- sample_q + concat -> h [N,256] ----------------
__global__ __launch_bounds__(256) void build_h_kernel(const float* __restrict__ x,
        const float* __restrict__ noise, const int* __restrict__ t,
        const float* __restrict__ sab, const float* __restrict__ somab,
        const float* __restrict__ temb, const float* __restrict__ stats,
        float* __restrict__ h, int n) {
    int wid = (blockIdx.x * blockDim.x + threadIdx.x) >> 6;
    int lane = threadIdx.x & 63;
    if (wid >= n) return;
    int tt = t[wid / NPG];
    float s1 = sab[tt], s2v = somab[tt];
    float2 nz = ((const float2*)noise)[(size_t)wid * 64 + lane];
    float s = nz.x + nz.y;
    float sq = nz.x * nz.x + nz.y * nz.y;
#pragma unroll
    for (int o = 1; o < 64; o <<= 1) { s += __shfl_xor(s, o); sq += __shfl_xor(sq, o); }
    float mu = s * (1.f / 128.f);
    float var = sq * (1.f / 128.f) - mu * mu;
    float r = rsqrtf(var + 1e-5f);
    int f0 = 2 * lane, f1 = f0 + 1;
    float y0 = (nz.x - mu) * r * stats[384 + f0] + stats[256 + f0];
    float y1 = (nz.y - mu) * r * stats[384 + f1] + stats[256 + f1];
    float2 xv = ((const float2*)x)[(size_t)wid * 64 + lane];
    float sg0 = (xv.x > 0.f) ? 1.f : ((xv.x < 0.f) ? -1.f : 0.f);
    float sg1 = (xv.y > 0.f) ? 1.f : ((xv.y < 0.f) ? -1.f : 0.f);
    float n0 = sg0 * fabsf(y0);
    float n1 = sg1 * fabsf(y1);
    float2 xt = make_float2(s1 * xv.x + s2v * n0, s1 * xv.y + s2v * n1);
    ((float2*)(h + (size_t)wid * 256))[lane] = xt;
    float2 te = ((const float2*)(temb + (size_t)tt * 128))[lane];
    ((float2*)(h + (size_t)wid * 256 + 128))[lane] = te;
}

// ---------------- CSR build ----------------
__global__ void hist_kernel(const int* __restrict__ dst, int* __restrict__ counts, int e) {
    int i = blockIdx.x * blockDim.x + threadIdx.x;
    if (i < e) atomicAdd(&counts[dst[i]], 1);
}

__global__ __launch_bounds__(1024) void scan_kernel(const int* __restrict__ counts,
        int* __restrict__ indptr, int* __restrict__ cursor, int n) {
    __shared__ int sh[1024];
    __shared__ int carryS;
    int tid = threadIdx.x;
    if (tid == 0) carryS = 0;
    __syncthreads();
    for (int base = 0; base < n; base += 1024) {
        int i = base + tid;
        int v = (i < n) ? counts[i] : 0;
        sh[tid] = v;
        __syncthreads();
        for (int o = 1; o < 1024; o <<= 1) {
            int tv = (tid >= o) ? sh[tid - o] : 0;
            __syncthreads();
            sh[tid] += tv;
            __syncthreads();
        }
        int incl = sh[tid];
        int carryVal = carryS;
        __syncthreads();
        if (i < n) { int ex = carryVal + incl - v; indptr[i] = ex; cursor[i] = ex; }
        if (tid == 0) carryS += sh[1023];
        __syncthreads();
    }
    if (tid == 0) indptr[n] = carryS;
}

__global__ void scatter_kernel(const int* __restrict__ src, const int* __restrict__ dst,
                               int* __restrict__ cursor, int* __restrict__ csr_src, int e) {
    int i = blockIdx.x * blockDim.x + threadIdx.x;
    if (i < e) {
        int p = atomicAdd(&cursor[dst[i]], 1);
        csr_src[p] = src[i];
    }
}

// ---------------- fp32 tiled GEMM: C[M,128] = A[M,K] @ W[K,128] ----------------
// EPI: 0 none, 1 bias+relu, 2 bias
template<int K, int EPI>
__global__ __launch_bounds__(256) void gemm_kernel(const float* __restrict__ A,
        const float* __restrict__ W, const float* __restrict__ bias,
        float* __restrict__ C, int M) {
    __shared__ float As[32][65];
    __shared__ float Bs[32][128];
    int tid = threadIdx.x;
    int tx = tid & 15, ty = tid >> 4;
    int rowBase = blockIdx.x * 64;
    float acc[4][8] = {};
    for (int k0 = 0; k0 < K; k0 += 32) {
        int kk = tid & 31, rb = tid >> 5;
#pragma unroll
        for (int p = 0; p < 8; ++p) {
            int r = rb + p * 8;
            int gr = rowBase + r;
            As[kk][r] = (gr < M) ? A[(size_t)gr * K + k0 + kk] : 0.f;
        }
        {
            int bk = tid >> 4;
            int c = (tid & 15) * 8;
#pragma unroll
            for (int p = 0; p < 2; ++p) {
                const float* srcp = W + (size_t)(k0 + bk + p * 16) * 128 + c;
                float4 v0 = *(const float4*)srcp;
                float4 v1 = *(const float4*)(srcp + 4);
                *(float4*)&Bs[bk + p * 16][c] = v0;
                *(float4*)&Bs[bk + p * 16][c + 4] = v1;
            }
        }
        __syncthreads();
#pragma unroll
        for (int k = 0; k < 32; ++k) {
            float av[4];
#pragma unroll
            for (int i = 0; i < 4; ++i) av[i] = As[k][ty * 4 + i];
            float4 b0 = *(const float4*)&Bs[k][tx * 8];
            float4 b1 = *(const float4*)&Bs[k][tx * 8 + 4];
            float bv[8] = {b0.x, b0.y, b0.z, b0.w, b1.x, b1.y, b1.z, b1.w};
#pragma unroll
            for (int i = 0; i < 4; ++i)
#pragma unroll
                for (int j = 0; j < 8; ++j) acc[i][j] = fmaf(av[i], bv[j], acc[i][j]);
        }
        __syncthreads();
    }
#pragma unroll
    for (int i = 0; i < 4; ++i) {
        int gr = rowBase + ty * 4 + i;
        if (gr >= M) continue;
#pragma unroll
        for (int j0 = 0; j0 < 8; j0 += 4) {
            int c = tx * 8 + j0;
            float4 v = make_float4(acc[i][j0], acc[i][j0 + 1], acc[i][j0 + 2], acc[i][j0 + 3]);
            if (EPI) { v.x += bias[c]; v.y += bias[c + 1]; v.z += bias[c + 2]; v.w += bias[c + 3]; }
            if (EPI == 1) {
                v.x = fmaxf(v.x, 0.f); v.y = fmaxf(v.y, 0.f);
                v.z = fmaxf(v.z, 0.f); v.w = fmaxf(v.w, 0.f);
            }
            *(float4*)&C[(size_t)gr * 128 + c] = v;
        }
    }
}

// ---------------- GATv2 per-destination-node online softmax + aggregate ----------------
__global__ __launch_bounds__(256) void gat_kernel(const float* __restrict__ fs,
        const float* __restrict__ fd, const float* __restrict__ a,
        const float* __restrict__ bias, const int* __restrict__ indptr,
        const int* __restrict__ csr_src, float* __restrict__ rst, int n) {
    int wid = (blockIdx.x * blockDim.x + threadIdx.x) >> 6;
    int lane = threadIdx.x & 63;
    if (wid >= n) return;
    int beg = indptr[wid], end = indptr[wid + 1];
    float2 fdv = ((const float2*)fd)[(size_t)wid * 64 + lane];
    float a0 = a[2 * lane], a1 = a[2 * lane + 1];
    float m = -INFINITY, den = 0.f, acc0 = 0.f, acc1 = 0.f;
    float2 v = make_float2(0.f, 0.f);
    if (beg < end) {
        int s = csr_src[beg];
        v = ((const float2*)fs)[(size_t)s * 64 + lane];
    }
    for (int j = beg; j < end; ++j) {
        float2 cur = v;
        if (j + 1 < end) {
            int s2 = csr_src[j + 1];
            v = ((const float2*)fs)[(size_t)s2 * 64 + lane];
        }
        float t0 = cur.x + fdv.x; t0 = (t0 > 0.f ? t0 : 0.2f * t0) * a0;
        float t1 = cur.y + fdv.y; t1 = (t1 > 0.f ? t1 : 0.2f * t1) * a1;
        float p = t0 + t1;
        p += __shfl_xor(p, 1); p += __shfl_xor(p, 2);
        p += __shfl_xor(p, 4); p += __shfl_xor(p, 8);   // head-sum (16-lane group)
        float nm = fmaxf(m, p);
        float sc = __expf(m - nm);
        float w = __expf(p - nm);
        den = den * sc + w;
        acc0 = acc0 * sc + w * cur.x;
        acc1 = acc1 * sc + w * cur.y;
        m = nm;
    }
    float r0 = (den > 0.f) ? acc0 / den : 0.f;
    float r1 = (den > 0.f) ? acc1 / den : 0.f;
    r0 = gelu_exact(r0 + bias[2 * lane]);
    r1 = gelu_exact(r1 + bias[2 * lane + 1]);
    ((float2*)rst)[(size_t)wid * 64 + lane] = make_float2(r0, r1);
}

// ---------------- LayerNorm (optional residual add), affine ----------------
__global__ __launch_bounds__(256) void ln_kernel(const float* __restrict__ in,
        const float* __restrict__ res, const float* __restrict__ g,
        const float* __restrict__ be, float* __restrict__ out, int n) {
    int wid = (blockIdx.x * blockDim.x + threadIdx.x) >> 6;
    int lane = threadIdx.x & 63;
    if (wid >= n) return;
    float2 v = ((const float2*)in)[(size_t)wid * 64 + lane];
    if (res) {
        float2 rr = ((const float2*)res)[(size_t)wid * 64 + lane];
        v.x += rr.x; v.y += rr.y;
    }
    float s = v.x + v.y;
    float sq = v.x * v.x + v.y * v.y;
#pragma unroll
    for (int o = 1; o < 64; o <<= 1) { s += __shfl_xor(s, o); sq += __shfl_xor(sq, o); }
    float mu = s * (1.f / 128.f);
    float var = sq * (1.f / 128.f) - mu * mu;
    float r = rsqrtf(var + 1e-5f);
    int f0 = 2 * lane, f1 = f0 + 1;
    float o0 = (v.x - mu) * r * g[f0] + be[f0];
    float o1 = (v.y - mu) * r * g[f1] + be[f1];
    ((float2*)out)[(size_t)wid * 64 + lane] = make_float2(o0, o1);
}

// ---------------- loss ----------------
__global__ __launch_bounds__(256) void loss_partial_kernel(const float* __restrict__ out,
        const float* __restrict__ x, float* __restrict__ partials, int n) {
    __shared__ float sm[8];
    int lane = threadIdx.x & 63;
    int wv = threadIdx.x >> 6;
    int gw = blockIdx.x * 4 + wv;
    float d2 = 0.f, closs = 0.f;
    for (int row = gw; row < n; row += 4096) {
        float2 o = ((const float2*)out)[(size_t)row * 64 + lane];
        float2 xv = ((const float2*)x)[(size_t)row * 64 + lane];
        float e0 = o.x - xv.x, e1 = o.y - xv.y;
        d2 += e0 * e0 + e1 * e1;
        float oo = o.x * o.x + o.y * o.y;
        float xx = xv.x * xv.x + xv.y * xv.y;
        float ox = o.x * xv.x + o.y * xv.y;
#pragma unroll
        for (int s = 1; s < 64; s <<= 1) {
            oo += __shfl_xor(oo, s); xx += __shfl_xor(xx, s); ox += __shfl_xor(ox, s);
        }
        float no = fmaxf(sqrtf(oo), 1e-12f);
        float nx = fmaxf(sqrtf(xx), 1e-12f);
        float cs = 1.f - ox / (no * nx);
        closs += cs * cs;
    }
#pragma unroll
    for (int s = 1; s < 64; s <<= 1) d2 += __shfl_xor(d2, s);
    if (lane == 0) { sm[wv] = d2; sm[4 + wv] = closs; }
    __syncthreads();
    if (threadIdx.x == 0) {
        partials[2 * blockIdx.x] = sm[0] + sm[1] + sm[2] + sm[3];
        partials[2 * blockIdx.x + 1] = sm[4] + sm[5] + sm[6] + sm[7];
    }
}

__global__ __launch_bounds__(1024) void loss_final_kernel(const float* __restrict__ partials,
        float* __restrict__ outp, int nb, int n) {
    __shared__ double sd[32];
    int tid = threadIdx.x;
    double m = 0.0, c = 0.0;
    for (int i = tid; i < nb; i += 1024) { m += partials[2 * i]; c += partials[2 * i + 1]; }
#pragma unroll
    for (int s = 1; s < 64; s <<= 1) { m += __shfl_xor(m, s); c += __shfl_xor(c, s); }
    int wv = tid >> 6, lane = tid & 63;
    if (lane == 0) { sd[wv] = m; sd[16 + wv] = c; }
    __syncthreads();
    if (tid == 0) {
        double mt = 0.0, ct = 0.0;
        for (int i = 0; i < 16; ++i) { mt += sd[i]; ct += sd[16 + i]; }
        outp[0] = (float)(mt / ((double)n * 128.0) + 0.1 * ct / (double)n);
    }
}

extern "C" void kernel_launch(void* const* d_in, const int* in_sizes, int n_in,
                              void* d_out, int out_size, void* d_ws, size_t ws_size,
                              hipStream_t stream) {
    const int N = NN, E = EE;
    const float* x     = (const float*)d_in[0];
    const float* noise = (const float*)d_in[1];
    const int*   src   = (const int*)d_in[2];
    const int*   dst   = (const int*)d_in[3];
    const int*   t     = (const int*)d_in[4];
    const float* sab   = (const float*)d_in[5];
    const float* somab = (const float*)d_in[6];
    const float* temb  = (const float*)d_in[7];
    const float* Ws0   = (const float*)d_in[8];
    const float* Wd0   = (const float*)d_in[9];
    const float* a0    = (const float*)d_in[10];
    const float* b0    = (const float*)d_in[11];
    const float* g0    = (const float*)d_in[12];
    const float* be0   = (const float*)d_in[13];
    const float* Ws1   = (const float*)d_in[14];
    const float* Wd1   = (const float*)d_in[15];
    const float* a1    = (const float*)d_in[16];
    const float* b1    = (const float*)d_in[17];
    const float* g1    = (const float*)d_in[18];
    const float* be1   = (const float*)d_in[19];
    const float* Wo1   = (const float*)d_in[20];
    const float* bo1   = (const float*)d_in[21];
    const float* Wo2   = (const float*)d_in[22];
    const float* bo2   = (const float*)d_in[23];

    float* ws = (float*)d_ws;
    float* h    = ws;                                   // N*256
    float* fs   = h  + (size_t)N * 256;                 // N*128
    float* fd   = fs + (size_t)N * 128;                 // N*128
    float* P    = fd + (size_t)N * 128;                 // rst0 -> h1 (in-place LN)
    float* Q    = P  + (size_t)N * 128;                 // rst1 -> h2 (in-place LN)
    float* z    = h;                                    // reuse h (free after layer-0 GEMMs)
    float* outb = h + (size_t)N * 128;                  // reuse h second half
    float* stats    = Q + (size_t)N * 128;              // 512 floats: sum,sumsq,miu,std
    float* partials = stats + 512;                      // 2*1024 floats
    int* counts  = (int*)(partials + 2048);             // N
    int* indptr  = counts + N;                          // N+1
    int* cursor  = indptr + N + 1;                      // N
    int* csr_src = cursor + N;                          // E

    hipMemsetAsync(stats, 0, 512 * sizeof(float), stream);
    hipMemsetAsync(counts, 0, (size_t)N * sizeof(int), stream);

    // stats + h build
    colstats_kernel<<<(N + 511) / 512, 256, 0, stream>>>(x, stats, N);
    finalize_stats_kernel<<<1, 128, 0, stream>>>(stats, N);
    build_h_kernel<<<(N + 3) / 4, 256, 0, stream>>>(x, noise, t, sab, somab, temb, stats, h, N);

    // CSR by dst
    hist_kernel<<<(E + 255) / 256, 256, 0, stream>>>(dst, counts, E);
    scan_kernel<<<1, 1024, 0, stream>>>(counts, indptr, cursor, N);
    scatter_kernel<<<(E + 255) / 256, 256, 0, stream>>>(src, dst, cursor, csr_src, E);

    int gemmGrid = (N + 63) / 64;
    // layer 0
    gemm_kernel<256, 0><<<gemmGrid, 256, 0, stream>>>(h, Ws0, nullptr, fs, N);
    gemm_kernel<256, 0><<<gemmGrid, 256, 0, stream>>>(h, Wd0, nullptr, fd, N);
    gat_kernel<<<(N + 3) / 4, 256, 0, stream>>>(fs, fd, a0, b0, indptr, csr_src, P, N);
    ln_kernel<<<(N + 3) / 4, 256, 0, stream>>>(P, nullptr, g0, be0, P, N);

    // layer 1
    gemm_kernel<128, 0><<<gemmGrid, 256, 0, stream>>>(P, Ws1, nullptr, fs, N);
    gemm_kernel<128, 0><<<gemmGrid, 256, 0, stream>>>(P, Wd1, nullptr, fd, N);
    gat_kernel<<<(N + 3) / 4, 256, 0, stream>>>(fs, fd, a1, b1, indptr, csr_src, Q, N);
    ln_kernel<<<(N + 3) / 4, 256, 0, stream>>>(Q, P, g1, be1, Q, N);

    // MLP head
    gemm_kernel<128, 1><<<gemmGrid, 256, 0, stream>>>(Q, Wo1, bo1, z, N);
    gemm_kernel<128, 2><<<gemmGrid, 256, 0, stream>>>(z, Wo2, bo2, outb, N);

    // loss
    loss_partial_kernel<<<1024, 256, 0, stream>>>(outb, x, partials, N);
    loss_final_kernel<<<1, 1024, 0, stream>>>(partials, (float*)d_out, 1024, N);
}

// Round 2
// 525.014 us; speedup vs baseline: 1.5082x; 1.5082x over previous
//
#include <hip/hip_runtime.h>
#include <hip/hip_bf16.h>
#include <math.h>

#define NN 50000
#define EE 800000
#define NPG 5000

typedef short bf16x8 __attribute__((ext_vector_type(8)));
typedef float f32x4 __attribute__((ext_vector_type(4)));

__device__ __forceinline__ float gelu_exact(float v) {
    return 0.5f * v * (1.0f + erff(v * 0.70710678118654752440f));
}

__device__ __forceinline__ ushort f2b(float f) {
    union { float f; uint u; } v; v.f = f;
    uint r = (v.u + 0x7fffu + ((v.u >> 16) & 1)) >> 16;
    return (ushort)r;
}
__device__ __forceinline__ uint pack2(float a, float b) {
    return (uint)f2b(a) | ((uint)f2b(b) << 16);
}
__device__ __forceinline__ float blo(uint u) {
    union { uint u; float f; } v; v.u = u << 16; return v.f;
}
__device__ __forceinline__ float bhi(uint u) {
    union { uint u; float f; } v; v.u = u & 0xffff0000u; return v.f;
}

// ---------------- column stats of x: sum, sumsq per column ----------------
__global__ __launch_bounds__(256) void colstats_kernel(const float* __restrict__ x,
                                                       float* __restrict__ sums, int n) {
    int col = threadIdx.x & 127;
    int half = threadIdx.x >> 7;
    int rowEnd = min(blockIdx.x * 512 + 512, n);
    float s = 0.f, s2 = 0.f;
    for (int r = blockIdx.x * 512 + half; r < rowEnd; r += 2) {
        float v = x[(size_t)r * 128 + col];
        s += v; s2 += v * v;
    }
    atomicAdd(&sums[col], s);
    atomicAdd(&sums[128 + col], s2);
}

__global__ void finalize_stats_kernel(float* __restrict__ stats, int n) {
    int c = threadIdx.x;   // 128 threads
    float sum = stats[c], sumsq = stats[128 + c];
    float mu = sum / (float)n;
    float var = (sumsq - sum * sum / (float)n) / (float)(n - 1);
    stats[256 + c] = mu;
    stats[384 + c] = sqrtf(fmaxf(var, 0.f));
}

// ---------------- sample_q + concat -> h bf16 [N,256] ----------------
__global__ __launch_bounds__(256) void build_h_kernel(const float* __restrict__ x,
        const float* __restrict__ noise, const int* __restrict__ t,
        const float* __restrict__ sab, const float* __restrict__ somab,
        const float* __restrict__ temb, const float* __restrict__ stats,
        ushort* __restrict__ h, int n) {
    int wid = (blockIdx.x * blockDim.x + threadIdx.x) >> 6;
    int lane = threadIdx.x & 63;
    if (wid >= n) return;
    int tt = t[wid / NPG];
    float s1 = sab[tt], s2v = somab[tt];
    float2 nz = ((const float2*)noise)[(size_t)wid * 64 + lane];
    float s = nz.x + nz.y;
    float sq = nz.x * nz.x + nz.y * nz.y;
#pragma unroll
    for (int o = 1; o < 64; o <<= 1) { s += __shfl_xor(s, o); sq += __shfl_xor(sq, o); }
    float mu = s * (1.f / 128.f);
    float var = sq * (1.f / 128.f) - mu * mu;
    float r = rsqrtf(var + 1e-5f);
    int f0 = 2 * lane, f1 = f0 + 1;
    float y0 = (nz.x - mu) * r * stats[384 + f0] + stats[256 + f0];
    float y1 = (nz.y - mu) * r * stats[384 + f1] + stats[256 + f1];
    float2 xv = ((const float2*)x)[(size_t)wid * 64 + lane];
    float sg0 = (xv.x > 0.f) ? 1.f : ((xv.x < 0.f) ? -1.f : 0.f);
    float sg1 = (xv.y > 0.f) ? 1.f : ((xv.y < 0.f) ? -1.f : 0.f);
    float n0 = sg0 * fabsf(y0);
    float n1 = sg1 * fabsf(y1);
    float xt0 = s1 * xv.x + s2v * n0;
    float xt1 = s1 * xv.y + s2v * n1;
    uint* row = (uint*)(h + (size_t)wid * 256);
    row[lane] = pack2(xt0, xt1);
    float2 te = ((const float2*)(temb + (size_t)tt * 128))[lane];
    row[64 + lane] = pack2(te.x, te.y);
}

// ---------------- weight conversion: fp32 [K][128] -> bf16 transposed ----------------
__global__ __launch_bounds__(256) void convert_weights(const float* __restrict__ Ws0,
        const float* __restrict__ Wd0, const float* __restrict__ Ws1,
        const float* __restrict__ Wd1, const float* __restrict__ Wo1,
        const float* __restrict__ Wo2, ushort* __restrict__ Wt0,
        ushort* __restrict__ Wt1, ushort* __restrict__ Wo1t, ushort* __restrict__ Wo2t) {
    int i = blockIdx.x * 256 + threadIdx.x;
    if (i < 65536) {                       // Wt0 [256][256]
        int c = i >> 8, k = i & 255;
        const float* W = (c < 128) ? Ws0 : Wd0;
        Wt0[c * 256 + k] = f2b(W[k * 128 + (c & 127)]);
    } else if (i < 98304) {                // Wt1 [256][128]
        int j = i - 65536;
        int c = j >> 7, k = j & 127;
        const float* W = (c < 128) ? Ws1 : Wd1;
        Wt1[c * 128 + k] = f2b(W[k * 128 + (c & 127)]);
    } else if (i < 114688) {               // Wo1t [128][128]
        int j = i - 98304;
        int c = j >> 7, k = j & 127;
        Wo1t[c * 128 + k] = f2b(Wo1[k * 128 + c]);
    } else if (i < 131072) {               // Wo2t [128][128]
        int j = i - 114688;
        int c = j >> 7, k = j & 127;
        Wo2t[c * 128 + k] = f2b(Wo2[k * 128 + c]);
    }
}

// ---------------- CSR build ----------------
__global__ void hist_kernel(const int* __restrict__ dst, int* __restrict__ counts, int e) {
    int i = blockIdx.x * blockDim.x + threadIdx.x;
    if (i < e) atomicAdd(&counts[dst[i]], 1);
}

__global__ __launch_bounds__(1024) void scan_kernel(const int* __restrict__ counts,
        int* __restrict__ indptr, int* __restrict__ cursor, int n) {
    __shared__ int sh[1024];
    int tid = threadIdx.x;
    const int PER = (n + 1023) / 1024;
    int b = tid * PER, e = min(b + PER, n);
    int s = 0;
    for (int i = b; i < e; ++i) s += counts[i];
    sh[tid] = s;
    __syncthreads();
    for (int o = 1; o < 1024; o <<= 1) {
        int v = (tid >= o) ? sh[tid - o] : 0;
        __syncthreads();
        sh[tid] += v;
        __syncthreads();
    }
    int pre = (tid ? sh[tid - 1] : 0);
    for (int i = b; i < e; ++i) {
        indptr[i] = pre; cursor[i] = pre;
        pre += counts[i];
    }
    if (tid == 1023) indptr[n] = sh[1023];
}

__global__ void scatter_kernel(const int* __restrict__ src, const int* __restrict__ dst,
                               int* __restrict__ cursor, int* __restrict__ csr_src, int e) {
    int i = blockIdx.x * blockDim.x + threadIdx.x;
    if (i < e) {
        int p = atomicAdd(&cursor[dst[i]], 1);
        csr_src[p] = src[i];
    }
}

// ---------------- bf16 MFMA GEMM: C[M,NCOL] = A[M,K] @ Wt^T ----------------
// Wt is [NCOL][K] bf16 (transposed weights). EPI: 0 plain->bf16 (split C0/C1 if
// NCOL==256), 1 bias+relu->bf16 C0, 2 bias->fp32 Cf.
template<int K, int NCOL, int EPI>
__global__ __launch_bounds__(256, 2) void mfma_gemm(const ushort* __restrict__ A,
        const ushort* __restrict__ Wt, const float* __restrict__ bias,
        ushort* __restrict__ C0, ushort* __restrict__ C1,
        float* __restrict__ Cf, int M) {
    constexpr int NFRAG = NCOL / 16;
    constexpr int KSTEPS = K / 32;
    __shared__ ushort Bs[32 * NCOL];     // XOR-swizzled [col][kk]
    int tid = threadIdx.x;
    int wave = tid >> 6, lane = tid & 63;
    int l15 = lane & 15, g = lane >> 4;
    int rowBase = blockIdx.x * 64 + wave * 16;
    int r = rowBase + l15;
    int rc = min(r, M - 1);
    const ushort* Arow = A + (size_t)rc * K + g * 8;

    f32x4 acc[NFRAG] = {};

    for (int ks = 0; ks < KSTEPS; ++ks) {
        // stage B-tile [32 x NCOL] into LDS with XOR swizzle
#pragma unroll
        for (int i = 0; i < NCOL / 64; ++i) {
            int ch = tid + i * 256;
            int c = ch >> 2, q = ch & 3;
            float4 v = *(const float4*)(Wt + (size_t)c * K + ks * 32 + q * 8);
            int off = c * 64 + ((q * 16) ^ ((c & 7) << 4));
            *(float4*)((char*)Bs + off) = v;
        }
        __syncthreads();
        bf16x8 af = *(const bf16x8*)(Arow + ks * 32);
        int roff = l15 * 64 + ((g * 16) ^ ((l15 & 7) << 4));
#pragma unroll
        for (int n = 0; n < NFRAG; ++n) {
            bf16x8 bf = *(const bf16x8*)((const char*)Bs + n * 1024 + roff);
            acc[n] = __builtin_amdgcn_mfma_f32_16x16x32_bf16(af, bf, acc[n], 0, 0, 0);
        }
        __syncthreads();
    }

#pragma unroll
    for (int n = 0; n < NFRAG; ++n) {
        int col = n * 16 + l15;
#pragma unroll
        for (int j = 0; j < 4; ++j) {
            int row = rowBase + g * 4 + j;
            if (row < M) {
                float v = acc[n][j];
                if (EPI == 1) v = fmaxf(v + bias[col], 0.f);
                if (EPI == 2) v = v + bias[col];
                if (EPI == 2) {
                    Cf[(size_t)row * 128 + col] = v;
                } else {
                    ushort bv = f2b(v);
                    if (NCOL == 256) {
                        if (n < 8) C0[(size_t)row * 128 + col] = bv;
                        else       C1[(size_t)row * 128 + col - 128] = bv;
                    } else {
                        C0[(size_t)row * 128 + col] = bv;
                    }
                }
            }
        }
    }
}

// ---------------- GATv2: per-dst online aggregate (bf16 features) ----------------
__global__ __launch_bounds__(256) void gat_kernel(const ushort* __restrict__ fs,
        const ushort* __restrict__ fd, const float* __restrict__ a,
        const float* __restrict__ bias, const int* __restrict__ indptr,
        const int* __restrict__ csr_src, float* __restrict__ rst, int n) {
    int wid = (blockIdx.x * blockDim.x + threadIdx.x) >> 6;
    int lane = threadIdx.x & 63;
    if (wid >= n) return;
    int beg = indptr[wid], cnt = indptr[wid + 1] - beg;
    const int* ip = csr_src + beg;
    uint fdu = ((const uint*)fd)[(size_t)wid * 64 + lane];
    float fd0 = blo(fdu), fd1 = bhi(fdu);
    float a0 = a[2 * lane], a1 = a[2 * lane + 1];
    const uint* fsu = (const uint*)fs;
    float den = 0.f, acc0 = 0.f, acc1 = 0.f;
    int s0 = (0 < cnt) ? ip[0] : 0;
    int s1 = (1 < cnt) ? ip[1] : 0;
    int s2 = (2 < cnt) ? ip[2] : 0;
    int s3 = (3 < cnt) ? ip[3] : 0;
    uint v0 = fsu[(size_t)s0 * 64 + lane];
    uint v1 = fsu[(size_t)s1 * 64 + lane];
    uint v2 = fsu[(size_t)s2 * 64 + lane];
    uint v3 = fsu[(size_t)s3 * 64 + lane];
    int i0 = (4 < cnt) ? ip[4] : 0;
    int i1 = (5 < cnt) ? ip[5] : 0;
    int i2 = (6 < cnt) ? ip[6] : 0;
    int i3 = (7 < cnt) ? ip[7] : 0;
    for (int j = 0; j < cnt; ++j) {
        uint cur = v0;
        v0 = v1; v1 = v2; v2 = v3;
        v3 = fsu[(size_t)i0 * 64 + lane];
        i0 = i1; i1 = i2; i2 = i3;
        i3 = (j + 8 < cnt) ? ip[j + 8] : 0;
        float c0 = blo(cur), c1 = bhi(cur);
        float t0 = c0 + fd0; t0 = (t0 > 0.f ? t0 : 0.2f * t0) * a0;
        float t1 = c1 + fd1; t1 = (t1 > 0.f ? t1 : 0.2f * t1) * a1;
        float p = t0 + t1;
        p += __shfl_xor(p, 1); p += __shfl_xor(p, 2);
        p += __shfl_xor(p, 4); p += __shfl_xor(p, 8);   // 16-lane head sum
        float w = __expf(p);     // logits are O(0.1): no max-subtraction needed
        den += w;
        acc0 = fmaf(w, c0, acc0);
        acc1 = fmaf(w, c1, acc1);
    }
    float inv = (cnt > 0) ? 1.f / den : 0.f;
    float r0 = gelu_exact(acc0 * inv + bias[2 * lane]);
    float r1 = gelu_exact(acc1 * inv + bias[2 * lane + 1]);
    ((float2*)rst)[(size_t)wid * 64 + lane] = make_float2(r0, r1);
}

// ---------------- LayerNorm (optional residual), fp32 and/or bf16 out ----------------
__global__ __launch_bounds__(256) void ln_kernel(const float* __restrict__ in,
        const float* __restrict__ res, const float* __restrict__ g,
        const float* __restrict__ be, float* __restrict__ outF,
        ushort* __restrict__ outB, int n) {
    int wid = (blockIdx.x * blockDim.x + threadIdx.x) >> 6;
    int lane = threadIdx.x & 63;
    if (wid >= n) return;
    float2 v = ((const float2*)in)[(size_t)wid * 64 + lane];
    if (res) {
        float2 rr = ((const float2*)res)[(size_t)wid * 64 + lane];
        v.x += rr.x; v.y += rr.y;
    }
    float s = v.x + v.y;
    float sq = v.x * v.x + v.y * v.y;
#pragma unroll
    for (int o = 1; o < 64; o <<= 1) { s += __shfl_xor(s, o); sq += __shfl_xor(sq, o); }
    float mu = s * (1.f / 128.f);
    float var = sq * (1.f / 128.f) - mu * mu;
    float r = rsqrtf(var + 1e-5f);
    int f0 = 2 * lane, f1 = f0 + 1;
    float o0 = (v.x - mu) * r * g[f0] + be[f0];
    float o1 = (v.y - mu) * r * g[f1] + be[f1];
    if (outF) ((float2*)outF)[(size_t)wid * 64 + lane] = make_float2(o0, o1);
    if (outB) ((uint*)outB)[(size_t)wid * 64 + lane] = pack2(o0, o1);
}

// ---------------- loss ----------------
__global__ __launch_bounds__(256) void loss_partial_kernel(const float* __restrict__ out,
        const float* __restrict__ x, float* __restrict__ partials, int n) {
    __shared__ float sm[8];
    int lane = threadIdx.x & 63;
    int wv = threadIdx.x >> 6;
    int gw = blockIdx.x * 4 + wv;
    float d2 = 0.f, closs = 0.f;
    for (int row = gw; row < n; row += 4096) {
        float2 o = ((const float2*)out)[(size_t)row * 64 + lane];
        float2 xv = ((const float2*)x)[(size_t)row * 64 + lane];
        float e0 = o.x - xv.x, e1 = o.y - xv.y;
        d2 += e0 * e0 + e1 * e1;
        float oo = o.x * o.x + o.y * o.y;
        float xx = xv.x * xv.x + xv.y * xv.y;
        float ox = o.x * xv.x + o.y * xv.y;
#pragma unroll
        for (int s = 1; s < 64; s <<= 1) {
            oo += __shfl_xor(oo, s); xx += __shfl_xor(xx, s); ox += __shfl_xor(ox, s);
        }
        float no = fmaxf(sqrtf(oo), 1e-12f);
        float nx = fmaxf(sqrtf(xx), 1e-12f);
        float cs = 1.f - ox / (no * nx);
        closs += cs * cs;
    }
#pragma unroll
    for (int s = 1; s < 64; s <<= 1) d2 += __shfl_xor(d2, s);
    if (lane == 0) { sm[wv] = d2; sm[4 + wv] = closs; }
    __syncthreads();
    if (threadIdx.x == 0) {
        partials[2 * blockIdx.x] = sm[0] + sm[1] + sm[2] + sm[3];
        partials[2 * blockIdx.x + 1] = sm[4] + sm[5] + sm[6] + sm[7];
    }
}

__global__ __launch_bounds__(1024) void loss_final_kernel(const float* __restrict__ partials,
        float* __restrict__ outp, int nb, int n) {
    __shared__ double sd[32];
    int tid = threadIdx.x;
    double m = 0.0, c = 0.0;
    for (int i = tid; i < nb; i += 1024) { m += partials[2 * i]; c += partials[2 * i + 1]; }
#pragma unroll
    for (int s = 1; s < 64; s <<= 1) { m += __shfl_xor(m, s); c += __shfl_xor(c, s); }
    int wv = tid >> 6, lane = tid & 63;
    if (lane == 0) { sd[wv] = m; sd[16 + wv] = c; }
    __syncthreads();
    if (tid == 0) {
        double mt = 0.0, ct = 0.0;
        for (int i = 0; i < 16; ++i) { mt += sd[i]; ct += sd[16 + i]; }
        outp[0] = (float)(mt / ((double)n * 128.0) + 0.1 * ct / (double)n);
    }
}

extern "C" void kernel_launch(void* const* d_in, const int* in_sizes, int n_in,
                              void* d_out, int out_size, void* d_ws, size_t ws_size,
                              hipStream_t stream) {
    const int N = NN, E = EE;
    const float* x     = (const float*)d_in[0];
    const float* noise = (const float*)d_in[1];
    const int*   src   = (const int*)d_in[2];
    const int*   dst   = (const int*)d_in[3];
    const int*   t     = (const int*)d_in[4];
    const float* sab   = (const float*)d_in[5];
    const float* somab = (const float*)d_in[6];
    const float* temb  = (const float*)d_in[7];
    const float* Ws0   = (const float*)d_in[8];
    const float* Wd0   = (const float*)d_in[9];
    const float* a0    = (const float*)d_in[10];
    const float* b0    = (const float*)d_in[11];
    const float* g0    = (const float*)d_in[12];
    const float* be0   = (const float*)d_in[13];
    const float* Ws1   = (const float*)d_in[14];
    const float* Wd1   = (const float*)d_in[15];
    const float* a1    = (const float*)d_in[16];
    const float* b1    = (const float*)d_in[17];
    const float* g1    = (const float*)d_in[18];
    const float* be1   = (const float*)d_in[19];
    const float* Wo1   = (const float*)d_in[20];
    const float* bo1   = (const float*)d_in[21];
    const float* Wo2   = (const float*)d_in[22];
    const float* bo2   = (const float*)d_in[23];

    float* ws = (float*)d_ws;
    // Region A [0 .. N*128 floats): h_bf16 [N][256] -> Pb bf16 [N][128] -> Q fp32 [N][128]
    ushort* hB  = (ushort*)ws;
    ushort* Pb  = (ushort*)ws;
    float*  Q   = ws;
    ushort* fsB = (ushort*)(ws + (size_t)N * 128);   // bf16 [N][128]; later Qb
    ushort* fdB = (ushort*)(ws + (size_t)N * 192);   // bf16 [N][128]; later z
    float*  P   = ws + (size_t)N * 256;              // fp32 [N][128]; later out
    float*  outb = P;
    ushort* Qb  = fsB;
    ushort* z   = fdB;
    float* wtail = ws + (size_t)N * 384;
    ushort* Wt0  = (ushort*)wtail;                   // [256][256] bf16
    ushort* Wt1  = (ushort*)(wtail + 32768);         // [256][128] bf16
    ushort* Wo1t = (ushort*)(wtail + 49152);         // [128][128] bf16
    ushort* Wo2t = (ushort*)(wtail + 57344);         // [128][128] bf16
    float* stats    = wtail + 65536;                 // 512
    float* partials = stats + 512;                   // 2048
    int* counts  = (int*)(partials + 2048);          // N
    int* indptr  = counts + N;                       // N+1
    int* cursor  = indptr + N + 1;                   // N
    int* csr_src = cursor + N;                       // E

    hipMemsetAsync(stats, 0, 512 * sizeof(float), stream);
    hipMemsetAsync(counts, 0, (size_t)N * sizeof(int), stream);

    colstats_kernel<<<(N + 511) / 512, 256, 0, stream>>>(x, stats, N);
    finalize_stats_kernel<<<1, 128, 0, stream>>>(stats, N);
    build_h_kernel<<<(N + 3) / 4, 256, 0, stream>>>(x, noise, t, sab, somab, temb, stats, hB, N);
    convert_weights<<<512, 256, 0, stream>>>(Ws0, Wd0, Ws1, Wd1, Wo1, Wo2, Wt0, Wt1, Wo1t, Wo2t);

    hist_kernel<<<(E + 255) / 256, 256, 0, stream>>>(dst, counts, E);
    scan_kernel<<<1, 1024, 0, stream>>>(counts, indptr, cursor, N);
    scatter_kernel<<<(E + 255) / 256, 256, 0, stream>>>(src, dst, cursor, csr_src, E);

    int gemmGrid = (N + 63) / 64;
    // layer 0: fs|fd = h @ [Ws0|Wd0]
    mfma_gemm<256, 256, 0><<<gemmGrid, 256, 0, stream>>>(hB, Wt0, nullptr, fsB, fdB, nullptr, N);
    gat_kernel<<<(N + 3) / 4, 256, 0, stream>>>(fsB, fdB, a0, b0, indptr, csr_src, P, N);
    ln_kernel<<<(N + 3) / 4, 256, 0, stream>>>(P, nullptr, g0, be0, P, Pb, N);

    // layer 1
    mfma_gemm<128, 256, 0><<<gemmGrid, 256, 0, stream>>>(Pb, Wt1, nullptr, fsB, fdB, nullptr, N);
    gat_kernel<<<(N + 3) / 4, 256, 0, stream>>>(fsB, fdB, a1, b1, indptr, csr_src, Q, N);
    ln_kernel<<<(N + 3) / 4, 256, 0, stream>>>(Q, P, g1, be1, nullptr, Qb, N);

    // MLP head
    mfma_gemm<128, 128, 1><<<gemmGrid, 256, 0, stream>>>(Qb, Wo1t, bo1, z, nullptr, nullptr, N);
    mfma_gemm<128, 128, 2><<<gemmGrid, 256, 0, stream>>>(z, Wo2t, bo2, nullptr, nullptr, outb, N);

    loss_partial_kernel<<<1024, 256, 0, stream>>>(outb, x, partials, N);
    loss_final_kernel<<<1, 1024, 0, stream>>>(partials, (float*)d_out, 1024, N);
}

// Round 3
// 426.362 us; speedup vs baseline: 1.8572x; 1.2314x over previous
//
#include <hip/hip_runtime.h>
#include <hip/hip_bf16.h>
#include <math.h>

#define NN 50000
#define EE 800000
#define NPG 5000

typedef short bf16x8 __attribute__((ext_vector_type(8)));
typedef float f32x4 __attribute__((ext_vector_type(4)));

__device__ __forceinline__ float gelu_exact(float v) {
    return 0.5f * v * (1.0f + erff(v * 0.70710678118654752440f));
}

__device__ __forceinline__ ushort f2b(float f) {
    union { float f; uint u; } v; v.f = f;
    uint r = (v.u + 0x7fffu + ((v.u >> 16) & 1)) >> 16;
    return (ushort)r;
}
__device__ __forceinline__ uint pack2(float a, float b) {
    return (uint)f2b(a) | ((uint)f2b(b) << 16);
}
__device__ __forceinline__ float blo(uint u) {
    union { uint u; float f; } v; v.u = u << 16; return v.f;
}
__device__ __forceinline__ float bhi(uint u) {
    union { uint u; float f; } v; v.u = u & 0xffff0000u; return v.f;
}

// ---------------- column stats of x: sum, sumsq per column ----------------
__global__ __launch_bounds__(256) void colstats_kernel(const float* __restrict__ x,
                                                       float* __restrict__ sums, int n) {
    int col = threadIdx.x & 127;
    int half = threadIdx.x >> 7;
    int rowEnd = min(blockIdx.x * 512 + 512, n);
    float s = 0.f, s2 = 0.f;
    for (int r = blockIdx.x * 512 + half; r < rowEnd; r += 2) {
        float v = x[(size_t)r * 128 + col];
        s += v; s2 += v * v;
    }
    atomicAdd(&sums[col], s);
    atomicAdd(&sums[128 + col], s2);
}

__global__ void finalize_stats_kernel(float* __restrict__ stats, int n) {
    int c = threadIdx.x;   // 128 threads
    float sum = stats[c], sumsq = stats[128 + c];
    float mu = sum / (float)n;
    float var = (sumsq - sum * sum / (float)n) / (float)(n - 1);
    stats[256 + c] = mu;
    stats[384 + c] = sqrtf(fmaxf(var, 0.f));
}

// ---------------- sample_q + concat -> h bf16 [N,256] ----------------
__global__ __launch_bounds__(256) void build_h_kernel(const float* __restrict__ x,
        const float* __restrict__ noise, const int* __restrict__ t,
        const float* __restrict__ sab, const float* __restrict__ somab,
        const float* __restrict__ temb, const float* __restrict__ stats,
        ushort* __restrict__ h, int n) {
    int wid = (blockIdx.x * blockDim.x + threadIdx.x) >> 6;
    int lane = threadIdx.x & 63;
    if (wid >= n) return;
    int tt = t[wid / NPG];
    float s1 = sab[tt], s2v = somab[tt];
    float2 nz = ((const float2*)noise)[(size_t)wid * 64 + lane];
    float s = nz.x + nz.y;
    float sq = nz.x * nz.x + nz.y * nz.y;
#pragma unroll
    for (int o = 1; o < 64; o <<= 1) { s += __shfl_xor(s, o); sq += __shfl_xor(sq, o); }
    float mu = s * (1.f / 128.f);
    float var = sq * (1.f / 128.f) - mu * mu;
    float r = rsqrtf(var + 1e-5f);
    int f0 = 2 * lane, f1 = f0 + 1;
    float y0 = (nz.x - mu) * r * stats[384 + f0] + stats[256 + f0];
    float y1 = (nz.y - mu) * r * stats[384 + f1] + stats[256 + f1];
    float2 xv = ((const float2*)x)[(size_t)wid * 64 + lane];
    float sg0 = (xv.x > 0.f) ? 1.f : ((xv.x < 0.f) ? -1.f : 0.f);
    float sg1 = (xv.y > 0.f) ? 1.f : ((xv.y < 0.f) ? -1.f : 0.f);
    float n0 = sg0 * fabsf(y0);
    float n1 = sg1 * fabsf(y1);
    float xt0 = s1 * xv.x + s2v * n0;
    float xt1 = s1 * xv.y + s2v * n1;
    uint* row = (uint*)(h + (size_t)wid * 256);
    row[lane] = pack2(xt0, xt1);
    float2 te = ((const float2*)(temb + (size_t)tt * 128))[lane];
    row[64 + lane] = pack2(te.x, te.y);
}

// ---------------- weight conversion: fp32 [K][128] -> bf16 transposed ----------------
__global__ __launch_bounds__(256) void convert_weights(const float* __restrict__ Ws0,
        const float* __restrict__ Wd0, const float* __restrict__ Ws1,
        const float* __restrict__ Wd1, const float* __restrict__ Wo1,
        const float* __restrict__ Wo2, ushort* __restrict__ Wt0,
        ushort* __restrict__ Wt1, ushort* __restrict__ Wo1t, ushort* __restrict__ Wo2t) {
    int i = blockIdx.x * 256 + threadIdx.x;
    if (i < 65536) {                       // Wt0 [256][256]
        int c = i >> 8, k = i & 255;
        const float* W = (c < 128) ? Ws0 : Wd0;
        Wt0[c * 256 + k] = f2b(W[k * 128 + (c & 127)]);
    } else if (i < 98304) {                // Wt1 [256][128]
        int j = i - 65536;
        int c = j >> 7, k = j & 127;
        const float* W = (c < 128) ? Ws1 : Wd1;
        Wt1[c * 128 + k] = f2b(W[k * 128 + (c & 127)]);
    } else if (i < 114688) {               // Wo1t [128][128]
        int j = i - 98304;
        int c = j >> 7, k = j & 127;
        Wo1t[c * 128 + k] = f2b(Wo1[k * 128 + c]);
    } else if (i < 131072) {               // Wo2t [128][128]
        int j = i - 114688;
        int c = j >> 7, k = j & 127;
        Wo2t[c * 128 + k] = f2b(Wo2[k * 128 + c]);
    }
}

// ---------------- CSR build ----------------
__global__ void hist_kernel(const int* __restrict__ dst, int* __restrict__ counts, int e) {
    int i = blockIdx.x * blockDim.x + threadIdx.x;
    if (i < e) atomicAdd(&counts[dst[i]], 1);
}

// 3-phase scan: reduce -> offsets -> apply
__global__ __launch_bounds__(1024) void scan_reduce_kernel(const int* __restrict__ counts,
        int* __restrict__ blockSums, int n) {
    int i = blockIdx.x * 1024 + threadIdx.x;
    int v = (i < n) ? counts[i] : 0;
#pragma unroll
    for (int o = 32; o > 0; o >>= 1) v += __shfl_down(v, o);
    __shared__ int sh[16];
    int lane = threadIdx.x & 63, wv = threadIdx.x >> 6;
    if (lane == 0) sh[wv] = v;
    __syncthreads();
    if (threadIdx.x == 0) {
        int s = 0;
#pragma unroll
        for (int k = 0; k < 16; ++k) s += sh[k];
        blockSums[blockIdx.x] = s;
    }
}

__global__ __launch_bounds__(64) void scan_offsets_kernel(const int* __restrict__ blockSums,
        int* __restrict__ blockOffs, int* __restrict__ indptr, int nb, int n) {
    int tid = threadIdx.x;
    int v = (tid < nb) ? blockSums[tid] : 0;
    int incl = v;
#pragma unroll
    for (int o = 1; o < 64; o <<= 1) {
        int tv = __shfl_up(incl, o);
        if (tid >= o) incl += tv;
    }
    if (tid < nb) blockOffs[tid] = incl - v;
    if (tid == 63) indptr[n] = incl;       // grand total
}

__global__ __launch_bounds__(1024) void scan_apply_kernel(const int* __restrict__ counts,
        const int* __restrict__ blockOffs, int* __restrict__ indptr,
        int* __restrict__ cursor, int n) {
    int tid = threadIdx.x;
    int i = blockIdx.x * 1024 + tid;
    int v = (i < n) ? counts[i] : 0;
    int lane = tid & 63, wv = tid >> 6;
    int incl = v;
#pragma unroll
    for (int o = 1; o < 64; o <<= 1) {
        int tv = __shfl_up(incl, o);
        if (lane >= o) incl += tv;
    }
    __shared__ int wsum[16];
    __shared__ int woff[16];
    if (lane == 63) wsum[wv] = incl;
    __syncthreads();
    if (tid == 0) {
        int s = 0;
#pragma unroll
        for (int k = 0; k < 16; ++k) { woff[k] = s; s += wsum[k]; }
    }
    __syncthreads();
    int ex = incl - v + woff[wv] + blockOffs[blockIdx.x];
    if (i < n) { indptr[i] = ex; cursor[i] = ex; }
}

__global__ void scatter_kernel(const int* __restrict__ src, const int* __restrict__ dst,
                               int* __restrict__ cursor, int* __restrict__ csr_src, int e) {
    int i = blockIdx.x * blockDim.x + threadIdx.x;
    if (i < e) {
        int p = atomicAdd(&cursor[dst[i]], 1);
        csr_src[p] = src[i];
    }
}

// ---------------- bf16 MFMA GEMM: C[M,NCOL] = A[M,K] @ Wt^T ----------------
// Wt is [NCOL][K] bf16 (transposed weights). EPI: 0 plain->bf16 (split C0/C1 if
// NCOL==256), 1 bias+relu->bf16 C0, 2 bias->fp32 Cf.
template<int K, int NCOL, int EPI>
__global__ __launch_bounds__(256, 2) void mfma_gemm(const ushort* __restrict__ A,
        const ushort* __restrict__ Wt, const float* __restrict__ bias,
        ushort* __restrict__ C0, ushort* __restrict__ C1,
        float* __restrict__ Cf, int M) {
    constexpr int NFRAG = NCOL / 16;
    constexpr int KSTEPS = K / 32;
    __shared__ ushort Bs[32 * NCOL];     // XOR-swizzled [col][kk]
    int tid = threadIdx.x;
    int wave = tid >> 6, lane = tid & 63;
    int l15 = lane & 15, g = lane >> 4;
    int rowBase = blockIdx.x * 64 + wave * 16;
    int r = rowBase + l15;
    int rc = min(r, M - 1);
    const ushort* Arow = A + (size_t)rc * K + g * 8;

    f32x4 acc[NFRAG] = {};

    for (int ks = 0; ks < KSTEPS; ++ks) {
        // stage B-tile [32 x NCOL] into LDS with XOR swizzle
#pragma unroll
        for (int i = 0; i < NCOL / 64; ++i) {
            int ch = tid + i * 256;
            int c = ch >> 2, q = ch & 3;
            float4 v = *(const float4*)(Wt + (size_t)c * K + ks * 32 + q * 8);
            int off = c * 64 + ((q * 16) ^ ((c & 7) << 4));
            *(float4*)((char*)Bs + off) = v;
        }
        __syncthreads();
        bf16x8 af = *(const bf16x8*)(Arow + ks * 32);
        int roff = l15 * 64 + ((g * 16) ^ ((l15 & 7) << 4));
#pragma unroll
        for (int n = 0; n < NFRAG; ++n) {
            bf16x8 bf = *(const bf16x8*)((const char*)Bs + n * 1024 + roff);
            acc[n] = __builtin_amdgcn_mfma_f32_16x16x32_bf16(af, bf, acc[n], 0, 0, 0);
        }
        __syncthreads();
    }

#pragma unroll
    for (int n = 0; n < NFRAG; ++n) {
        int col = n * 16 + l15;
#pragma unroll
        for (int j = 0; j < 4; ++j) {
            int row = rowBase + g * 4 + j;
            if (row < M) {
                float v = acc[n][j];
                if (EPI == 1) v = fmaxf(v + bias[col], 0.f);
                if (EPI == 2) v = v + bias[col];
                if (EPI == 2) {
                    Cf[(size_t)row * 128 + col] = v;
                } else {
                    ushort bv = f2b(v);
                    if (NCOL == 256) {
                        if (n < 8) C0[(size_t)row * 128 + col] = bv;
                        else       C1[(size_t)row * 128 + col - 128] = bv;
                    } else {
                        C0[(size_t)row * 128 + col] = bv;
                    }
                }
            }
        }
    }
}

// ---------------- GATv2: per-dst online aggregate (bf16 features) ----------------
__global__ __launch_bounds__(256) void gat_kernel(const ushort* __restrict__ fs,
        const ushort* __restrict__ fd, const float* __restrict__ a,
        const float* __restrict__ bias, const int* __restrict__ indptr,
        const int* __restrict__ csr_src, float* __restrict__ rst, int n) {
    int wid = (blockIdx.x * blockDim.x + threadIdx.x) >> 6;
    int lane = threadIdx.x & 63;
    if (wid >= n) return;
    int beg = indptr[wid], cnt = indptr[wid + 1] - beg;
    const int* ip = csr_src + beg;
    uint fdu = ((const uint*)fd)[(size_t)wid * 64 + lane];
    float fd0 = blo(fdu), fd1 = bhi(fdu);
    float a0 = a[2 * lane], a1 = a[2 * lane + 1];
    const uint* fsu = (const uint*)fs;
    float den = 0.f, acc0 = 0.f, acc1 = 0.f;
    int s0 = (0 < cnt) ? ip[0] : 0;
    int s1 = (1 < cnt) ? ip[1] : 0;
    int s2 = (2 < cnt) ? ip[2] : 0;
    int s3 = (3 < cnt) ? ip[3] : 0;
    uint v0 = fsu[(size_t)s0 * 64 + lane];
    uint v1 = fsu[(size_t)s1 * 64 + lane];
    uint v2 = fsu[(size_t)s2 * 64 + lane];
    uint v3 = fsu[(size_t)s3 * 64 + lane];
    int i0 = (4 < cnt) ? ip[4] : 0;
    int i1 = (5 < cnt) ? ip[5] : 0;
    int i2 = (6 < cnt) ? ip[6] : 0;
    int i3 = (7 < cnt) ? ip[7] : 0;
    for (int j = 0; j < cnt; ++j) {
        uint cur = v0;
        v0 = v1; v1 = v2; v2 = v3;
        v3 = fsu[(size_t)i0 * 64 + lane];
        i0 = i1; i1 = i2; i2 = i3;
        i3 = (j + 8 < cnt) ? ip[j + 8] : 0;
        float c0 = blo(cur), c1 = bhi(cur);
        float t0 = c0 + fd0; t0 = (t0 > 0.f ? t0 : 0.2f * t0) * a0;
        float t1 = c1 + fd1; t1 = (t1 > 0.f ? t1 : 0.2f * t1) * a1;
        float p = t0 + t1;
        p += __shfl_xor(p, 1); p += __shfl_xor(p, 2);
        p += __shfl_xor(p, 4); p += __shfl_xor(p, 8);   // 16-lane head sum
        float w = __expf(p);     // logits are O(0.1): no max-subtraction needed
        den += w;
        acc0 = fmaf(w, c0, acc0);
        acc1 = fmaf(w, c1, acc1);
    }
    float inv = (cnt > 0) ? 1.f / den : 0.f;
    float r0 = gelu_exact(acc0 * inv + bias[2 * lane]);
    float r1 = gelu_exact(acc1 * inv + bias[2 * lane + 1]);
    ((float2*)rst)[(size_t)wid * 64 + lane] = make_float2(r0, r1);
}

// ---------------- LayerNorm (optional residual), fp32 and/or bf16 out ----------------
__global__ __launch_bounds__(256) void ln_kernel(const float* __restrict__ in,
        const float* __restrict__ res, const float* __restrict__ g,
        const float* __restrict__ be, float* __restrict__ outF,
        ushort* __restrict__ outB, int n) {
    int wid = (blockIdx.x * blockDim.x + threadIdx.x) >> 6;
    int lane = threadIdx.x & 63;
    if (wid >= n) return;
    float2 v = ((const float2*)in)[(size_t)wid * 64 + lane];
    if (res) {
        float2 rr = ((const float2*)res)[(size_t)wid * 64 + lane];
        v.x += rr.x; v.y += rr.y;
    }
    float s = v.x + v.y;
    float sq = v.x * v.x + v.y * v.y;
#pragma unroll
    for (int o = 1; o < 64; o <<= 1) { s += __shfl_xor(s, o); sq += __shfl_xor(sq, o); }
    float mu = s * (1.f / 128.f);
    float var = sq * (1.f / 128.f) - mu * mu;
    float r = rsqrtf(var + 1e-5f);
    int f0 = 2 * lane, f1 = f0 + 1;
    float o0 = (v.x - mu) * r * g[f0] + be[f0];
    float o1 = (v.y - mu) * r * g[f1] + be[f1];
    if (outF) ((float2*)outF)[(size_t)wid * 64 + lane] = make_float2(o0, o1);
    if (outB) ((uint*)outB)[(size_t)wid * 64 + lane] = pack2(o0, o1);
}

// ---------------- loss ----------------
__global__ __launch_bounds__(256) void loss_partial_kernel(const float* __restrict__ out,
        const float* __restrict__ x, float* __restrict__ partials, int n) {
    __shared__ float sm[8];
    int lane = threadIdx.x & 63;
    int wv = threadIdx.x >> 6;
    int gw = blockIdx.x * 4 + wv;
    float d2 = 0.f, closs = 0.f;
    for (int row = gw; row < n; row += 4096) {
        float2 o = ((const float2*)out)[(size_t)row * 64 + lane];
        float2 xv = ((const float2*)x)[(size_t)row * 64 + lane];
        float e0 = o.x - xv.x, e1 = o.y - xv.y;
        d2 += e0 * e0 + e1 * e1;
        float oo = o.x * o.x + o.y * o.y;
        float xx = xv.x * xv.x + xv.y * xv.y;
        float ox = o.x * xv.x + o.y * xv.y;
#pragma unroll
        for (int s = 1; s < 64; s <<= 1) {
            oo += __shfl_xor(oo, s); xx += __shfl_xor(xx, s); ox += __shfl_xor(ox, s);
        }
        float no = fmaxf(sqrtf(oo), 1e-12f);
        float nx = fmaxf(sqrtf(xx), 1e-12f);
        float cs = 1.f - ox / (no * nx);
        closs += cs * cs;
    }
#pragma unroll
    for (int s = 1; s < 64; s <<= 1) d2 += __shfl_xor(d2, s);
    if (lane == 0) { sm[wv] = d2; sm[4 + wv] = closs; }
    __syncthreads();
    if (threadIdx.x == 0) {
        partials[2 * blockIdx.x] = sm[0] + sm[1] + sm[2] + sm[3];
        partials[2 * blockIdx.x + 1] = sm[4] + sm[5] + sm[6] + sm[7];
    }
}

__global__ __launch_bounds__(1024) void loss_final_kernel(const float* __restrict__ partials,
        float* __restrict__ outp, int nb, int n) {
    __shared__ double sd[32];
    int tid = threadIdx.x;
    double m = 0.0, c = 0.0;
    for (int i = tid; i < nb; i += 1024) { m += partials[2 * i]; c += partials[2 * i + 1]; }
#pragma unroll
    for (int s = 1; s < 64; s <<= 1) { m += __shfl_xor(m, s); c += __shfl_xor(c, s); }
    int wv = tid >> 6, lane = tid & 63;
    if (lane == 0) { sd[wv] = m; sd[16 + wv] = c; }
    __syncthreads();
    if (tid == 0) {
        double mt = 0.0, ct = 0.0;
        for (int i = 0; i < 16; ++i) { mt += sd[i]; ct += sd[16 + i]; }
        outp[0] = (float)(mt / ((double)n * 128.0) + 0.1 * ct / (double)n);
    }
}

extern "C" void kernel_launch(void* const* d_in, const int* in_sizes, int n_in,
                              void* d_out, int out_size, void* d_ws, size_t ws_size,
                              hipStream_t stream) {
    const int N = NN, E = EE;
    const float* x     = (const float*)d_in[0];
    const float* noise = (const float*)d_in[1];
    const int*   src   = (const int*)d_in[2];
    const int*   dst   = (const int*)d_in[3];
    const int*   t     = (const int*)d_in[4];
    const float* sab   = (const float*)d_in[5];
    const float* somab = (const float*)d_in[6];
    const float* temb  = (const float*)d_in[7];
    const float* Ws0   = (const float*)d_in[8];
    const float* Wd0   = (const float*)d_in[9];
    const float* a0    = (const float*)d_in[10];
    const float* b0    = (const float*)d_in[11];
    const float* g0    = (const float*)d_in[12];
    const float* be0   = (const float*)d_in[13];
    const float* Ws1   = (const float*)d_in[14];
    const float* Wd1   = (const float*)d_in[15];
    const float* a1    = (const float*)d_in[16];
    const float* b1    = (const float*)d_in[17];
    const float* g1    = (const float*)d_in[18];
    const float* be1   = (const float*)d_in[19];
    const float* Wo1   = (const float*)d_in[20];
    const float* bo1   = (const float*)d_in[21];
    const float* Wo2   = (const float*)d_in[22];
    const float* bo2   = (const float*)d_in[23];

    float* ws = (float*)d_ws;
    // Region A [0 .. N*128 floats): h_bf16 [N][256] -> Pb bf16 [N][128] -> Q fp32 [N][128]
    ushort* hB  = (ushort*)ws;
    ushort* Pb  = (ushort*)ws;
    float*  Q   = ws;
    ushort* fsB = (ushort*)(ws + (size_t)N * 128);   // bf16 [N][128]; later Qb
    ushort* fdB = (ushort*)(ws + (size_t)N * 192);   // bf16 [N][128]; later z
    float*  P   = ws + (size_t)N * 256;              // fp32 [N][128]; later out
    float*  outb = P;
    ushort* Qb  = fsB;
    ushort* z   = fdB;
    float* wtail = ws + (size_t)N * 384;
    ushort* Wt0  = (ushort*)wtail;                   // [256][256] bf16
    ushort* Wt1  = (ushort*)(wtail + 32768);         // [256][128] bf16
    ushort* Wo1t = (ushort*)(wtail + 49152);         // [128][128] bf16
    ushort* Wo2t = (ushort*)(wtail + 57344);         // [128][128] bf16
    float* stats    = wtail + 65536;                 // 512
    float* partials = stats + 512;                   // 2048
    int* counts  = (int*)(partials + 2048);          // N
    int* indptr  = counts + N;                       // N+1
    int* cursor  = indptr + N + 1;                   // N
    int* csr_src = cursor + N;                       // E
    int* blockSums = csr_src + E;                    // 64
    int* blockOffs = blockSums + 64;                 // 64

    hipMemsetAsync(stats, 0, 512 * sizeof(float), stream);
    hipMemsetAsync(counts, 0, (size_t)N * sizeof(int), stream);

    colstats_kernel<<<(N + 511) / 512, 256, 0, stream>>>(x, stats, N);
    finalize_stats_kernel<<<1, 128, 0, stream>>>(stats, N);
    build_h_kernel<<<(N + 3) / 4, 256, 0, stream>>>(x, noise, t, sab, somab, temb, stats, hB, N);
    convert_weights<<<512, 256, 0, stream>>>(Ws0, Wd0, Ws1, Wd1, Wo1, Wo2, Wt0, Wt1, Wo1t, Wo2t);

    hist_kernel<<<(E + 255) / 256, 256, 0, stream>>>(dst, counts, E);
    int nScanB = (N + 1023) / 1024;
    scan_reduce_kernel<<<nScanB, 1024, 0, stream>>>(counts, blockSums, N);
    scan_offsets_kernel<<<1, 64, 0, stream>>>(blockSums, blockOffs, indptr, nScanB, N);
    scan_apply_kernel<<<nScanB, 1024, 0, stream>>>(counts, blockOffs, indptr, cursor, N);
    scatter_kernel<<<(E + 255) / 256, 256, 0, stream>>>(src, dst, cursor, csr_src, E);

    int gemmGrid = (N + 63) / 64;
    // layer 0: fs|fd = h @ [Ws0|Wd0]
    mfma_gemm<256, 256, 0><<<gemmGrid, 256, 0, stream>>>(hB, Wt0, nullptr, fsB, fdB, nullptr, N);
    gat_kernel<<<(N + 3) / 4, 256, 0, stream>>>(fsB, fdB, a0, b0, indptr, csr_src, P, N);
    ln_kernel<<<(N + 3) / 4, 256, 0, stream>>>(P, nullptr, g0, be0, P, Pb, N);

    // layer 1
    mfma_gemm<128, 256, 0><<<gemmGrid, 256, 0, stream>>>(Pb, Wt1, nullptr, fsB, fdB, nullptr, N);
    gat_kernel<<<(N + 3) / 4, 256, 0, stream>>>(fsB, fdB, a1, b1, indptr, csr_src, Q, N);
    ln_kernel<<<(N + 3) / 4, 256, 0, stream>>>(Q, P, g1, be1, nullptr, Qb, N);

    // MLP head
    mfma_gemm<128, 128, 1><<<gemmGrid, 256, 0, stream>>>(Qb, Wo1t, bo1, z, nullptr, nullptr, N);
    mfma_gemm<128, 128, 2><<<gemmGrid, 256, 0, stream>>>(z, Wo2t, bo2, nullptr, nullptr, outb, N);

    loss_partial_kernel<<<1024, 256, 0, stream>>>(outb, x, partials, N);
    loss_final_kernel<<<1, 1024, 0, stream>>>(partials, (float*)d_out, 1024, N);
}